// Round 7
// baseline (523.697 us; speedup 1.0000x reference)
//
#include <hip/hip_runtime.h>
#include <hip/hip_bf16.h>
#include <hip/hip_cooperative_groups.h>

namespace cg = cooperative_groups;

#define SEQ 1024
#define DIM 128
#define NEG_SLOPE 0.1f

typedef __bf16 bf16x8 __attribute__((ext_vector_type(8)));
typedef float f32x4v __attribute__((ext_vector_type(4)));

// One LDS pool shared by all phases (max member 16896 B)
union LdsAll {
    unsigned       pk_pack[32][33];     // adj pack staging (4224 B)
    unsigned short T[DIM][66];          // nodes transpose staging (16896 B)
    unsigned       pk_g[1024];          // gcn: packed mask words (4096 B)
    unsigned short pooled[32][136];     // gcn: phase-2 A operand (8704 B)
};

__device__ __forceinline__ unsigned short bfb(float f) {
    __bf16 h = (__bf16)f;
    return __builtin_bit_cast(unsigned short, h);
}
__device__ __forceinline__ unsigned mpack(int x0, int x1) {
    unsigned m0 = (x0 != 0) ? 0x3F80u : 0u;
    unsigned m1 = (x1 != 0) ? 0x3F80u : 0u;
    return m0 | (m1 << 16);
}
// Raw barrier: LDS-drain only (no vmcnt(0) drain)
__device__ __forceinline__ void bar() {
    asm volatile("s_waitcnt lgkmcnt(0)" ::: "memory");
    __builtin_amdgcn_s_barrier();
    __builtin_amdgcn_sched_barrier(0);
}

// ---------------- phase-A job 1: adj -> packT (coalesced + ballot) ----------
// Bit layout: word(itile) bit (8j + b) == column k = 4b + j (verified round 6).
__device__ __forceinline__ void do_adj_pack(const int* __restrict__ adj,
                                            unsigned* __restrict__ packT,
                                            int bid, int tid, LdsAll& L) {
    const int b    = bid >> 5;
    const int slab = bid & 31;
    const int o0   = slab << 5;
    const int wave = tid >> 6;
    const int lane = tid & 63;

    const int* base = adj + (size_t)b * SEQ * SEQ;
    #pragma unroll
    for (int r = 0; r < 8; ++r) {
        const int* row = base + (size_t)(o0 + wave * 8 + r) * SEQ;
        int4 v[4];
        #pragma unroll
        for (int q = 0; q < 4; ++q)
            v[q] = *(const int4*)(row + q * 256 + lane * 4);   // 1KB/instr, contiguous
        #pragma unroll
        for (int q = 0; q < 4; ++q) {
            unsigned long long m0 = __ballot(v[q].x != 0);
            unsigned long long m1 = __ballot(v[q].y != 0);
            unsigned long long m2 = __ballot(v[q].z != 0);
            unsigned long long m3 = __ballot(v[q].w != 0);
            if (lane < 8) {
                const int sh = 8 * lane;
                unsigned w = ((unsigned)(m0 >> sh) & 0xFFu)
                           | (((unsigned)(m1 >> sh) & 0xFFu) << 8)
                           | (((unsigned)(m2 >> sh) & 0xFFu) << 16)
                           | (((unsigned)(m3 >> sh) & 0xFFu) << 24);
                L.pk_pack[8 * q + lane][wave * 8 + r] = w;
            }
        }
    }
    __syncthreads();
    const int it = tid >> 3, oos = (tid & 7) * 4;
    uint4 w4 = make_uint4(L.pk_pack[it][oos], L.pk_pack[it][oos + 1],
                          L.pk_pack[it][oos + 2], L.pk_pack[it][oos + 3]);
    *(uint4*)(packT + (size_t)b * 32 * SEQ + (size_t)it * SEQ + o0 + oos) = w4;
}

// ---------------- phase-A job 2: nodes [b][o][d] f32 -> nodesT [b][d][o] bf16
__device__ __forceinline__ void do_nodes_t(const float* __restrict__ nodes,
                                           unsigned short* __restrict__ nodesT,
                                           int bid, int tid, LdsAll& L) {
    const int b  = bid >> 4;
    const int o0 = (bid & 15) << 6;
    const float* src = nodes + (size_t)b * SEQ * DIM;
    const int t = tid & 31;
    const int g = tid >> 5;

    float4 v[8];
    #pragma unroll
    for (int r = 0; r < 8; ++r)
        v[r] = *(const float4*)(src + (size_t)(o0 + g * 8 + r) * DIM + 4 * t);
    #pragma unroll
    for (int j = 0; j < 4; ++j) {
        #pragma unroll
        for (int p = 0; p < 4; ++p) {
            unsigned w = (unsigned)bfb(((const float*)&v[2 * p])[j]) |
                         ((unsigned)bfb(((const float*)&v[2 * p + 1])[j]) << 16);
            *(unsigned*)((unsigned char*)&L.T[0][0] + (size_t)(4 * t + j) * 132 + (g * 8 + 2 * p) * 2) = w;
        }
    }
    __syncthreads();
    const int d = tid >> 1, h = tid & 1;
    unsigned u[16];
    #pragma unroll
    for (int s = 0; s < 16; ++s)
        u[s] = *(const unsigned*)((const unsigned char*)&L.T[0][0] + (size_t)d * 132 + h * 64 + s * 4);
    unsigned short* dst = nodesT + (size_t)b * DIM * SEQ + (size_t)d * SEQ + o0 + h * 32;
    #pragma unroll
    for (int s = 0; s < 4; ++s) {
        uint4 q = make_uint4(u[4 * s], u[4 * s + 1], u[4 * s + 2], u[4 * s + 3]);
        *(uint4*)((unsigned char*)dst + s * 16) = q;
    }
}

// ---------------- phase-A job 3: W,B -> transposed bf16 [n][k] ---------------
__device__ __forceinline__ void do_wb(const float* __restrict__ W, const float* __restrict__ Bm,
                                      unsigned short* __restrict__ WT, unsigned short* __restrict__ BT,
                                      int wb_bid, int tid) {
    const int gid = wb_bid * 256 + tid;   // 64 blocks -> 16384 = 128*128
    const int n = gid >> 7, k = gid & 127;
    WT[gid] = bfb(W[k * DIM + n]);
    BT[gid] = bfb(Bm[k * DIM + n]);
}

// bit0 / bit4 extraction of pre-shifted packed words -> bf16 {0,1} pairs
__device__ __forceinline__ bf16x8 expand_lo(const uint4 Sa, const uint4 Sb) {
    union { unsigned u[4]; bf16x8 v; } r;
    r.u[0] = (Sa.x & 1u) * 0x3F80u | (Sa.y & 1u) * 0x3F800000u;
    r.u[1] = (Sa.z & 1u) * 0x3F80u | (Sa.w & 1u) * 0x3F800000u;
    r.u[2] = (Sb.x & 1u) * 0x3F80u | (Sb.y & 1u) * 0x3F800000u;
    r.u[3] = (Sb.z & 1u) * 0x3F80u | (Sb.w & 1u) * 0x3F800000u;
    return r.v;
}
__device__ __forceinline__ bf16x8 expand_hi(const uint4 Sa, const uint4 Sb) {
    union { unsigned u[4]; bf16x8 v; } r;   // (x&16)*0x3F8 == 0x3F80 at bit4
    r.u[0] = (Sa.x & 16u) * 0x3F8u | (Sa.y & 16u) * 0x3F80000u;
    r.u[1] = (Sa.z & 16u) * 0x3F8u | (Sa.w & 16u) * 0x3F80000u;
    r.u[2] = (Sb.x & 16u) * 0x3F8u | (Sb.y & 16u) * 0x3F80000u;
    r.u[3] = (Sb.z & 16u) * 0x3F8u | (Sb.w & 16u) * 0x3F80000u;
    return r.v;
}

// ---------------- phase B: the MFMA kernel (round-6 logic) -------------------
__device__ __forceinline__ void do_gcn(const float* __restrict__ nodes,
                                       const unsigned* __restrict__ packT,
                                       const unsigned short* __restrict__ nodesT,
                                       const unsigned short* __restrict__ WT,
                                       const unsigned short* __restrict__ BT,
                                       float* __restrict__ out,
                                       int bid, int tid, LdsAll& L) {
    const int xcd   = bid & 7;
    const int slot  = bid >> 3;
    const int batch = ((slot >> 5) << 3) | xcd;
    const int itile = slot & 31;
    const int i0    = itile << 5;

    const int wave = tid >> 6;
    const int lane = tid & 63;
    const int lrow = lane & 15;
    const int quad = lane >> 4;
    const int p0   = 8 * (lrow & 3) + (lrow >> 2);   // permuted bit pos (rows 0..15)

    const float*          __restrict__ nodes_b = nodes  + (size_t)batch * SEQ * DIM;
    const unsigned*       __restrict__ pk_b    = packT  + (size_t)batch * 32 * SEQ + (size_t)itile * SEQ;
    const unsigned short* __restrict__ nT_b    = nodesT + (size_t)batch * DIM * SEQ;

    ((uint4*)L.pk_g)[tid] = ((const uint4*)pk_b)[tid];   // 4KB staged once
    bar();

    f32x4v acc[2][2] = {};
    f32x4v acc_cnt[2] = {};
    bf16x8 ones;
    #pragma unroll
    for (int j = 0; j < 8; ++j) ones[j] = __builtin_bit_cast(__bf16, (unsigned short)0x3F80);

    bf16x8 bvA[4], bvB[4];

    auto load_bv = [&](int c, bf16x8 (&bv)[4]) {
        const unsigned short* pn = nT_b + (size_t)(wave * 32 + lrow) * SEQ + c * 64 + quad * 8;
        bv[0] = *(const bf16x8*)(pn);
        bv[1] = *(const bf16x8*)(pn + 16 * SEQ);
        bv[2] = *(const bf16x8*)(pn + 32);
        bv[3] = *(const bf16x8*)(pn + 16 * SEQ + 32);
    };
    auto compute = [&](int c, const bf16x8 (&bv)[4]) {
        #pragma unroll
        for (int kk = 0; kk < 2; ++kk) {
            const uint4 Wa = *(const uint4*)&L.pk_g[c * 64 + kk * 32 + quad * 8];
            const uint4 Wb = *(const uint4*)&L.pk_g[c * 64 + kk * 32 + quad * 8 + 4];
            uint4 Sa, Sb;
            Sa.x = Wa.x >> p0; Sa.y = Wa.y >> p0; Sa.z = Wa.z >> p0; Sa.w = Wa.w >> p0;
            Sb.x = Wb.x >> p0; Sb.y = Wb.y >> p0; Sb.z = Wb.z >> p0; Sb.w = Wb.w >> p0;
            bf16x8 av0 = expand_lo(Sa, Sb);   // == expand at bit p0
            bf16x8 av1 = expand_hi(Sa, Sb);   // == expand at bit p0+4
            acc[0][0] = __builtin_amdgcn_mfma_f32_16x16x32_bf16(av0, bv[2 * kk + 0], acc[0][0], 0, 0, 0);
            acc[0][1] = __builtin_amdgcn_mfma_f32_16x16x32_bf16(av0, bv[2 * kk + 1], acc[0][1], 0, 0, 0);
            acc[1][0] = __builtin_amdgcn_mfma_f32_16x16x32_bf16(av1, bv[2 * kk + 0], acc[1][0], 0, 0, 0);
            acc[1][1] = __builtin_amdgcn_mfma_f32_16x16x32_bf16(av1, bv[2 * kk + 1], acc[1][1], 0, 0, 0);
            acc_cnt[0] = __builtin_amdgcn_mfma_f32_16x16x32_bf16(av0, ones, acc_cnt[0], 0, 0, 0);
            acc_cnt[1] = __builtin_amdgcn_mfma_f32_16x16x32_bf16(av1, ones, acc_cnt[1], 0, 0, 0);
        }
    };

    load_bv(0, bvA);
    load_bv(1, bvB);
    for (int cc = 0; cc < 8; ++cc) {
        const int c0 = 2 * cc;
        compute(c0, bvA);
        if (c0 + 2 < 16) load_bv(c0 + 2, bvA);
        compute(c0 + 1, bvB);
        if (c0 + 3 < 16) load_bv(c0 + 3, bvB);
    }

    bar();   // done reading L.pk_g before pooled (aliased) is written

    #pragma unroll
    for (int mf = 0; mf < 2; ++mf) {
        #pragma unroll
        for (int r = 0; r < 4; ++r) {
            const int row = mf * 16 + quad * 4 + r;
            const float cnt = acc_cnt[mf][r];
            const float inv = (cnt > 0.5f) ? 1.0f / cnt : 0.0f;
            #pragma unroll
            for (int nf = 0; nf < 2; ++nf)
                L.pooled[row][wave * 32 + nf * 16 + lrow] = bfb(acc[mf][nf][r] * inv);
        }
    }
    bar();

    f32x4v acc2[2][2] = {};
    const int dn = wave * 32 + lrow;

    #pragma unroll
    for (int ks = 0; ks < 4; ++ks) {
        const int k0 = ks * 32 + quad * 8;
        bf16x8 av[2], bv2[2];
        #pragma unroll
        for (int mf = 0; mf < 2; ++mf)
            av[mf] = *(const bf16x8*)((const unsigned char*)&L.pooled[0][0] + (mf * 16 + lrow) * 272 + k0 * 2);
        #pragma unroll
        for (int nf = 0; nf < 2; ++nf)
            bv2[nf] = *(const bf16x8*)(WT + (size_t)(dn + nf * 16) * DIM + k0);
        #pragma unroll
        for (int mf = 0; mf < 2; ++mf)
            #pragma unroll
            for (int nf = 0; nf < 2; ++nf)
                acc2[mf][nf] = __builtin_amdgcn_mfma_f32_16x16x32_bf16(av[mf], bv2[nf], acc2[mf][nf], 0, 0, 0);
    }
    #pragma unroll
    for (int ks = 0; ks < 4; ++ks) {
        const int k0 = ks * 32 + quad * 8;
        bf16x8 av[2], bv2[2];
        #pragma unroll
        for (int mf = 0; mf < 2; ++mf) {
            const float* p = nodes_b + (size_t)(i0 + mf * 16 + lrow) * DIM + k0;
            const float4 f1 = *(const float4*)p;
            const float4 f2 = *(const float4*)(p + 4);
            av[mf][0] = (__bf16)f1.x; av[mf][1] = (__bf16)f1.y;
            av[mf][2] = (__bf16)f1.z; av[mf][3] = (__bf16)f1.w;
            av[mf][4] = (__bf16)f2.x; av[mf][5] = (__bf16)f2.y;
            av[mf][6] = (__bf16)f2.z; av[mf][7] = (__bf16)f2.w;
        }
        #pragma unroll
        for (int nf = 0; nf < 2; ++nf)
            bv2[nf] = *(const bf16x8*)(BT + (size_t)(dn + nf * 16) * DIM + k0);
        #pragma unroll
        for (int mf = 0; mf < 2; ++mf)
            #pragma unroll
            for (int nf = 0; nf < 2; ++nf)
                acc2[mf][nf] = __builtin_amdgcn_mfma_f32_16x16x32_bf16(av[mf], bv2[nf], acc2[mf][nf], 0, 0, 0);
    }

    float* out_b = out + (size_t)batch * SEQ * DIM;
    #pragma unroll
    for (int mf = 0; mf < 2; ++mf) {
        #pragma unroll
        for (int nf = 0; nf < 2; ++nf) {
            const int col = wave * 32 + nf * 16 + lrow;
            #pragma unroll
            for (int r = 0; r < 4; ++r) {
                const int row = i0 + mf * 16 + quad * 4 + r;
                const float x = acc2[mf][nf][r];
                out_b[(size_t)row * DIM + col] = (x > 0.0f) ? x : NEG_SLOPE * x;
            }
        }
    }
}

// ---------------- merged cooperative kernel ---------------------------------
__global__ __launch_bounds__(256, 4)
void gcn_all(const float* __restrict__ nodes, const int* __restrict__ adj,
             const float* __restrict__ W, const float* __restrict__ Bm,
             unsigned* __restrict__ packT, unsigned short* __restrict__ nodesT,
             unsigned short* __restrict__ WT, unsigned short* __restrict__ BT,
             float* __restrict__ out)
{
    __shared__ LdsAll L;
    const int bid = blockIdx.x, tid = threadIdx.x;

    do_adj_pack(adj, packT, bid, tid, L);
    __syncthreads();                       // LDS reuse boundary
    if (bid < 512)       do_nodes_t(nodes, nodesT, bid, tid, L);
    else if (bid >= 960) do_wb(W, Bm, WT, BT, bid - 960, tid);

    __threadfence();                       // device-scope release of ws writes
    cg::this_grid().sync();

    do_gcn(nodes, packT, nodesT, WT, BT, out, bid, tid, L);
}

// ---------------- standalone wrappers (non-cooperative fallback) ------------
__global__ __launch_bounds__(256)
void adj_pack_k(const int* __restrict__ adj, unsigned* __restrict__ packT) {
    __shared__ LdsAll L;
    do_adj_pack(adj, packT, blockIdx.x, threadIdx.x, L);
}
__global__ __launch_bounds__(256)
void nodes_t_k(const float* __restrict__ nodes, unsigned short* __restrict__ nodesT) {
    __shared__ LdsAll L;
    do_nodes_t(nodes, nodesT, blockIdx.x, threadIdx.x, L);
}
__global__ __launch_bounds__(256)
void wb_k(const float* __restrict__ W, const float* __restrict__ Bm,
          unsigned short* __restrict__ WT, unsigned short* __restrict__ BT) {
    do_wb(W, Bm, WT, BT, blockIdx.x, threadIdx.x);
}
__global__ __launch_bounds__(256, 4)
void gcn_k(const float* __restrict__ nodes, const unsigned* __restrict__ packT,
           const unsigned short* __restrict__ nodesT, const unsigned short* __restrict__ WT,
           const unsigned short* __restrict__ BT, float* __restrict__ out) {
    __shared__ LdsAll L;
    do_gcn(nodes, packT, nodesT, WT, BT, out, blockIdx.x, threadIdx.x, L);
}

// ---------------- fallback (round-2 kernel, verbatim) if workspace too small
#define BUF_STRIDE 24576
#define NODES_OFF  8192
__device__ __forceinline__ int fb_swz(int row, int unit) {
    const int x  = row >> 2;
    const int fx = ((x & 3) | ((x & 1) << 2)) ^ ((x >> 2) & 7);
    return row * 128 + ((unit ^ fx) << 4);
}
__global__ __launch_bounds__(256, 2)
void gcn_fused_fb(const float* __restrict__ nodes, const int* __restrict__ adj,
                  const float* __restrict__ W, const float* __restrict__ Bm,
                  float* __restrict__ out)
{
    __shared__ alignas(16) unsigned char lds[2 * BUF_STRIDE];
    const int bid = blockIdx.x, xcd = bid & 7, slot = bid >> 3;
    const int batch = ((slot >> 4) << 3) | xcd, mtile = slot & 15, i0 = mtile << 6;
    const int tid = threadIdx.x, wave = tid >> 6, lane = tid & 63;
    const int wm = wave >> 1, wn = wave & 1, lrow = lane & 15, quad = lane >> 4;
    const int* __restrict__ adj_b = adj + (size_t)batch * SEQ * SEQ;
    const float* __restrict__ nodes_b = nodes + (size_t)batch * SEQ * DIM;
    const int a_row = (tid >> 4) * 4, a_col = (tid & 15) * 4;
    const int n_row = (tid >> 5) * 4, n_col = (tid & 31) * 4;
    const int m_unit = (tid >> 4) >> 1, m_sub = ((tid >> 4) & 1) * 8;
    const int n_unit = (tid >> 5) >> 1, n_sub = ((tid >> 5) & 1) * 8;
    f32x4v acc[2][4] = {}; f32x4v acc_cnt[2] = {};
    bf16x8 ones;
    #pragma unroll
    for (int j = 0; j < 8; ++j) ones[j] = __builtin_bit_cast(__bf16, (unsigned short)0x3F80);
    int4 A0[4], A1[4]; float4 N0[8], N1[8];
    auto load_chunk = [&](int o0, int4 (&A)[4], float4 (&N)[8]) {
        const int* pa = adj_b + (size_t)(o0 + a_row) * SEQ + (i0 + a_col);
        #pragma unroll
        for (int r = 0; r < 4; ++r) A[r] = *(const int4*)(pa + (size_t)r * SEQ);
        const float* pn = nodes_b + (size_t)(o0 + n_row) * DIM + n_col;
        #pragma unroll
        for (int it = 0; it < 2; ++it)
            #pragma unroll
            for (int r = 0; r < 4; ++r)
                N[it * 4 + r] = *(const float4*)(pn + (size_t)(it * 32 + r) * DIM);
    };
    auto write_lds = [&](int base, const int4 (&A)[4], const float4 (&N)[8]) {
        unsigned char* mb = lds + base; unsigned char* nb = lds + base + NODES_OFF;
        #pragma unroll
        for (int j = 0; j < 4; ++j) {
            uint2 w;
            w.x = mpack(((const int*)&A[0])[j], ((const int*)&A[1])[j]);
            w.y = mpack(((const int*)&A[2])[j], ((const int*)&A[3])[j]);
            *(uint2*)(mb + fb_swz(a_col + j, m_unit) + m_sub) = w;
        }
        #pragma unroll
        for (int it = 0; it < 2; ++it) {
            #pragma unroll
            for (int j = 0; j < 4; ++j) {
                uint2 w;
                w.x = (unsigned)bfb(((const float*)&N[it*4+0])[j]) | ((unsigned)bfb(((const float*)&N[it*4+1])[j]) << 16);
                w.y = (unsigned)bfb(((const float*)&N[it*4+2])[j]) | ((unsigned)bfb(((const float*)&N[it*4+3])[j]) << 16);
                *(uint2*)(nb + fb_swz(n_col + j, 4 * it + n_unit) + n_sub) = w;
            }
        }
    };
    auto compute = [&](int base) {
        const unsigned char* mb = lds + base; const unsigned char* nb = lds + base + NODES_OFF;
        #pragma unroll
        for (int kk = 0; kk < 2; ++kk) {
            bf16x8 av[2], bv[4];
            av[0] = *(const bf16x8*)(mb + fb_swz(wm * 32 + lrow, 4 * kk + quad));
            av[1] = *(const bf16x8*)(mb + fb_swz(wm * 32 + 16 + lrow, 4 * kk + quad));
            #pragma unroll
            for (int nf = 0; nf < 4; ++nf)
                bv[nf] = *(const bf16x8*)(nb + fb_swz(wn * 64 + nf * 16 + lrow, 4 * kk + quad));
            #pragma unroll
            for (int mf = 0; mf < 2; ++mf) {
                #pragma unroll
                for (int nf = 0; nf < 4; ++nf)
                    acc[mf][nf] = __builtin_amdgcn_mfma_f32_16x16x32_bf16(av[mf], bv[nf], acc[mf][nf], 0, 0, 0);
                acc_cnt[mf] = __builtin_amdgcn_mfma_f32_16x16x32_bf16(av[mf], ones, acc_cnt[mf], 0, 0, 0);
            }
        }
    };
    load_chunk(0, A0, N0); load_chunk(64, A1, N1);
    write_lds(0, A0, N0); load_chunk(128, A0, N0); bar();
    for (int cc = 0; cc < 8; ++cc) {
        const int c0 = cc * 2;
        compute(0); write_lds(BUF_STRIDE, A1, N1);
        if (c0 + 3 < 16) load_chunk((c0 + 3) * 64, A1, N1);
        bar();
        compute(BUF_STRIDE);
        if (c0 + 2 < 16) write_lds(0, A0, N0);
        if (c0 + 4 < 16) load_chunk((c0 + 4) * 64, A0, N0);
        bar();
    }
    unsigned short (*pooled)[136] = (unsigned short (*)[136])(void*)lds;
    #pragma unroll
    for (int mf = 0; mf < 2; ++mf)
        #pragma unroll
        for (int r = 0; r < 4; ++r) {
            const int row = wm * 32 + mf * 16 + quad * 4 + r;
            const float cnt = acc_cnt[mf][r];
            const float inv = (cnt > 0.5f) ? 1.0f / cnt : 0.0f;
            #pragma unroll
            for (int nf = 0; nf < 4; ++nf)
                pooled[row][wn * 64 + nf * 16 + lrow] = bfb(acc[mf][nf][r] * inv);
        }
    __syncthreads();
    f32x4v acc2[2][4] = {};
    const int d_b0 = wn * 64 + lrow;
    #pragma unroll
    for (int ks = 0; ks < 4; ++ks) {
        const int k0 = ks * 32 + quad * 8;
        bf16x8 av[2];
        #pragma unroll
        for (int mf = 0; mf < 2; ++mf)
            av[mf] = *(const bf16x8*)&pooled[wm * 32 + mf * 16 + lrow][k0];
        bf16x8 bv[4];
        const float* pw = W + (size_t)k0 * DIM + d_b0;
        #pragma unroll
        for (int nf = 0; nf < 4; ++nf)
            #pragma unroll
            for (int j = 0; j < 8; ++j) bv[nf][j] = (__bf16)pw[j * DIM + nf * 16];
        #pragma unroll
        for (int mf = 0; mf < 2; ++mf)
            #pragma unroll
            for (int nf = 0; nf < 4; ++nf)
                acc2[mf][nf] = __builtin_amdgcn_mfma_f32_16x16x32_bf16(av[mf], bv[nf], acc2[mf][nf], 0, 0, 0);
    }
    #pragma unroll
    for (int ks = 0; ks < 4; ++ks) {
        const int k0 = ks * 32 + quad * 8;
        bf16x8 av[2];
        #pragma unroll
        for (int mf = 0; mf < 2; ++mf) {
            const float* p = nodes_b + (size_t)(i0 + wm * 32 + mf * 16 + lrow) * DIM + k0;
            const float4 f1 = *(const float4*)p; const float4 f2 = *(const float4*)(p + 4);
            av[mf][0] = (__bf16)f1.x; av[mf][1] = (__bf16)f1.y;
            av[mf][2] = (__bf16)f1.z; av[mf][3] = (__bf16)f1.w;
            av[mf][4] = (__bf16)f2.x; av[mf][5] = (__bf16)f2.y;
            av[mf][6] = (__bf16)f2.z; av[mf][7] = (__bf16)f2.w;
        }
        bf16x8 bv[4];
        const float* pB = Bm + (size_t)k0 * DIM + d_b0;
        #pragma unroll
        for (int nf = 0; nf < 4; ++nf)
            #pragma unroll
            for (int j = 0; j < 8; ++j) bv[nf][j] = (__bf16)pB[j * DIM + nf * 16];
        #pragma unroll
        for (int mf = 0; mf < 2; ++mf)
            #pragma unroll
            for (int nf = 0; nf < 4; ++nf)
                acc2[mf][nf] = __builtin_amdgcn_mfma_f32_16x16x32_bf16(av[mf], bv[nf], acc2[mf][nf], 0, 0, 0);
    }
    float* out_b = out + (size_t)batch * SEQ * DIM;
    #pragma unroll
    for (int mf = 0; mf < 2; ++mf)
        #pragma unroll
        for (int nf = 0; nf < 4; ++nf) {
            const int col = wn * 64 + nf * 16 + lrow;
            #pragma unroll
            for (int r = 0; r < 4; ++r) {
                const int row = i0 + wm * 32 + mf * 16 + quad * 4 + r;
                const float x = acc2[mf][nf][r];
                out_b[(size_t)row * DIM + col] = (x > 0.0f) ? x : NEG_SLOPE * x;
            }
        }
}

extern "C" void kernel_launch(void* const* d_in, const int* in_sizes, int n_in,
                              void* d_out, int out_size, void* d_ws, size_t ws_size,
                              hipStream_t stream) {
    const float* nodes = (const float*)d_in[0];
    const int*   adj   = (const int*)d_in[1];
    const float* W     = (const float*)d_in[2];
    const float* Bm    = (const float*)d_in[3];
    float*       out   = (float*)d_out;

    const size_t PK_BYTES = (size_t)32 * 32 * SEQ * 4;        // 4 MB packT
    const size_t NT_BYTES = (size_t)32 * DIM * SEQ * 2;       // 8 MB nodesT
    const size_t WB_BYTES = (size_t)DIM * DIM * 2;            // 32 KB each
    const size_t NEED = PK_BYTES + NT_BYTES + 2 * WB_BYTES;   // ~12.6 MB

    if (d_ws != nullptr && ws_size >= NEED) {
        unsigned*       packT  = (unsigned*)d_ws;
        unsigned short* nodesT = (unsigned short*)((char*)d_ws + PK_BYTES);
        unsigned short* WT = (unsigned short*)((char*)d_ws + PK_BYTES + NT_BYTES);
        unsigned short* BT = (unsigned short*)((char*)d_ws + PK_BYTES + NT_BYTES + WB_BYTES);

        void* args[9];
        args[0] = (void*)&nodes;  args[1] = (void*)&adj;
        args[2] = (void*)&W;      args[3] = (void*)&Bm;
        args[4] = (void*)&packT;  args[5] = (void*)&nodesT;
        args[6] = (void*)&WT;     args[7] = (void*)&BT;
        args[8] = (void*)&out;
        hipError_t e = hipLaunchCooperativeKernel((const void*)gcn_all,
                                                  dim3(1024), dim3(256),
                                                  args, 0, stream);
        if (e != hipSuccess) {
            (void)hipGetLastError();   // clear sticky error, use 4-kernel path
            adj_pack_k<<<dim3(1024), dim3(256), 0, stream>>>(adj, packT);
            wb_k<<<dim3(64), dim3(256), 0, stream>>>(W, Bm, WT, BT);
            nodes_t_k<<<dim3(512), dim3(256), 0, stream>>>(nodes, nodesT);
            gcn_k<<<dim3(1024), dim3(256), 0, stream>>>(nodes, packT, nodesT, WT, BT, out);
        }
    } else {
        gcn_fused_fb<<<dim3(512), dim3(256), 0, stream>>>(nodes, adj, W, Bm, out);
    }
}

// Round 8
// 219.536 us; speedup vs baseline: 2.3855x; 2.3855x over previous
//
#include <hip/hip_runtime.h>
#include <hip/hip_bf16.h>

#define SEQ 1024
#define DIM 128
#define NEG_SLOPE 0.1f

typedef __bf16 bf16x8 __attribute__((ext_vector_type(8)));
typedef float f32x4v __attribute__((ext_vector_type(4)));

// LDS: double-buffered {mask_t 128i x 64o bf16 (16KB) + nodes_t 128d x 64o bf16 (16KB)}
// Row stride 128 B = 8 x 16B units, XOR-swizzled (round-2-verified scheme):
//   phys_unit = log_unit ^ fxv(row>>2)
#define BUF_STRIDE 32768
#define NODES_OFF  16384

__device__ __forceinline__ int fxv(int x) {
    return ((x & 3) | ((x & 1) << 2)) ^ ((x >> 2) & 7);
}
__device__ __forceinline__ int swz(int row, int unit) {
    return row * 128 + ((unit ^ fxv(row >> 2)) << 4);
}
// Raw barrier: LDS-drain only — no vmcnt(0), register prefetch stays in flight
__device__ __forceinline__ void bar() {
    asm volatile("s_waitcnt lgkmcnt(0)" ::: "memory");
    __builtin_amdgcn_s_barrier();
    __builtin_amdgcn_sched_barrier(0);
}
__device__ __forceinline__ unsigned short bfb(float f) {
    __bf16 h = (__bf16)f;
    return __builtin_bit_cast(unsigned short, h);
}
__device__ __forceinline__ unsigned mpack(int x0, int x1) {
    unsigned m0 = (x0 != 0) ? 0x3F80u : 0u;   // bf16 1.0
    unsigned m1 = (x1 != 0) ? 0x3F80u : 0u;
    return m0 | (m1 << 16);
}

// 128-i tile, 512 threads (8 waves: wm 0..3 x wn 0..1), grid 256 = 1 block/CU.
// Fabric traffic: adj 134 MB + nodes-f32 staging 8x/batch = 128 MB + out 16 MB
// (~295 MB vs round-2's 393 MB at the same ~6 TB/s fabric ceiling).
__global__ __launch_bounds__(512, 2)
void gcn_fused(const float* __restrict__ nodes,
               const int* __restrict__ adj,
               const float* __restrict__ W,
               const float* __restrict__ Bm,
               float* __restrict__ out)
{
    __shared__ alignas(16) unsigned char lds[2 * BUF_STRIDE];

    // XCD swizzle: all 8 i-tiles of a batch on one XCD (adj/nodes L2 locality)
    const int bid   = blockIdx.x;          // 256 = 32 batches x 8 itiles
    const int xcd   = bid & 7;
    const int slot  = bid >> 3;            // 0..31
    const int batch = ((slot >> 3) << 3) | xcd;   // [0,32)
    const int itile = slot & 7;            // [0,8)
    const int i0    = itile << 7;

    const int tid  = threadIdx.x;
    const int wave = tid >> 6;             // 0..7
    const int lane = tid & 63;
    const int wm   = wave >> 1;            // 0..3  (i 32-row slice)
    const int wn   = wave & 1;             // 0..1  (d 64-col slice)
    const int lrow = lane & 15;
    const int quad = lane >> 4;

    const int*   __restrict__ adj_b   = adj   + (size_t)batch * SEQ * SEQ;
    const float* __restrict__ nodes_b = nodes + (size_t)batch * SEQ * DIM;

    // staging mapping: 512 threads cover 64o x 128(i or d) per chunk
    const int a_row = (tid >> 5) * 4;      // o row group (16 groups x 4 = 64)
    const int a_col = (tid & 31) * 4;      // i group (int4) -> 128
    const int n_row = (tid >> 5) * 4;      // o row group
    const int n_col = (tid & 31) * 4;      // d group (float4) -> 128
    const int unit_s = (tid >> 5) >> 1;    // 16B unit of o-col in LDS row
    const int sub_s  = ((tid >> 5) & 1) * 8;

    f32x4v acc[2][4] = {};
    f32x4v acc_cnt[2] = {};
    bf16x8 ones;
    #pragma unroll
    for (int j = 0; j < 8; ++j) ones[j] = __builtin_bit_cast(__bf16, (unsigned short)0x3F80);

    // two named register staging sets (static indexing), 2-chunk prefetch
    int4   A0[4], A1[4];
    float4 N0[4], N1[4];

    auto load_chunk = [&](int o0, int4 (&A)[4], float4 (&N)[4]) {
        const int* pa = adj_b + (size_t)(o0 + a_row) * SEQ + (i0 + a_col);
        #pragma unroll
        for (int r = 0; r < 4; ++r) A[r] = *(const int4*)(pa + (size_t)r * SEQ);
        const float* pn = nodes_b + (size_t)(o0 + n_row) * DIM + n_col;
        #pragma unroll
        for (int r = 0; r < 4; ++r) N[r] = *(const float4*)(pn + (size_t)r * DIM);
    };

    auto write_lds = [&](int base, const int4 (&A)[4], const float4 (&N)[4]) {
        unsigned char* mb = lds + base;
        unsigned char* nb = lds + base + NODES_OFF;
        #pragma unroll
        for (int j = 0; j < 4; ++j) {
            uint2 w;
            w.x = mpack(((const int*)&A[0])[j], ((const int*)&A[1])[j]);
            w.y = mpack(((const int*)&A[2])[j], ((const int*)&A[3])[j]);
            *(uint2*)(mb + swz(a_col + j, unit_s) + sub_s) = w;
        }
        #pragma unroll
        for (int j = 0; j < 4; ++j) {
            uint2 w;
            w.x = (unsigned)bfb(((const float*)&N[0])[j]) |
                  ((unsigned)bfb(((const float*)&N[1])[j]) << 16);
            w.y = (unsigned)bfb(((const float*)&N[2])[j]) |
                  ((unsigned)bfb(((const float*)&N[3])[j]) << 16);
            *(uint2*)(nb + swz(n_col + j, unit_s) + sub_s) = w;
        }
    };

    auto compute = [&](int base) {
        const unsigned char* mb = lds + base;
        const unsigned char* nb = lds + base + NODES_OFF;
        #pragma unroll
        for (int kk = 0; kk < 2; ++kk) {
            bf16x8 av[2], bv[4];
            #pragma unroll
            for (int mf = 0; mf < 2; ++mf)
                av[mf] = *(const bf16x8*)(mb + swz(wm * 32 + mf * 16 + lrow, 4 * kk + quad));
            #pragma unroll
            for (int nf = 0; nf < 4; ++nf)
                bv[nf] = *(const bf16x8*)(nb + swz(wn * 64 + nf * 16 + lrow, 4 * kk + quad));
            #pragma unroll
            for (int mf = 0; mf < 2; ++mf) {
                #pragma unroll
                for (int nf = 0; nf < 4; ++nf)
                    acc[mf][nf] = __builtin_amdgcn_mfma_f32_16x16x32_bf16(av[mf], bv[nf], acc[mf][nf], 0, 0, 0);
                acc_cnt[mf] = __builtin_amdgcn_mfma_f32_16x16x32_bf16(av[mf], ones, acc_cnt[mf], 0, 0, 0);
            }
        }
    };

    // prologue: R0<-c0, R1<-c1; stage c0; R0<-c2  (2-deep in flight)
    load_chunk(0,   A0, N0);
    load_chunk(64,  A1, N1);
    write_lds(0, A0, N0);
    load_chunk(128, A0, N0);
    bar();

    for (int cc = 0; cc < 8; ++cc) {
        const int c0 = cc * 2;
        compute(0);
        write_lds(BUF_STRIDE, A1, N1);
        if (c0 + 3 < 16) load_chunk((c0 + 3) * 64, A1, N1);
        bar();
        compute(BUF_STRIDE);
        if (c0 + 2 < 16) write_lds(0, A0, N0);
        if (c0 + 4 < 16) load_chunk((c0 + 4) * 64, A0, N0);
        bar();
    }

    // poolsum -> pooled bf16 (divide by MFMA-computed in-degree)
    unsigned short (*pooled)[136] = (unsigned short (*)[136])(void*)lds;
    #pragma unroll
    for (int mf = 0; mf < 2; ++mf) {
        #pragma unroll
        for (int r = 0; r < 4; ++r) {
            const int row = wm * 32 + mf * 16 + quad * 4 + r;
            const float cnt = acc_cnt[mf][r];
            const float inv = (cnt > 0.5f) ? 1.0f / cnt : 0.0f;
            #pragma unroll
            for (int nf = 0; nf < 4; ++nf) {
                const int col = wn * 64 + nf * 16 + lrow;
                pooled[row][col] = bfb(acc[mf][nf][r] * inv);
            }
        }
    }
    bar();

    f32x4v acc2[2][4] = {};
    const int d_b0 = wn * 64 + lrow;

    // pooled @ W  (K=128)
    #pragma unroll
    for (int ks = 0; ks < 4; ++ks) {
        const int k0 = ks * 32 + quad * 8;
        bf16x8 av[2];
        #pragma unroll
        for (int mf = 0; mf < 2; ++mf)
            av[mf] = *(const bf16x8*)&pooled[wm * 32 + mf * 16 + lrow][k0];
        bf16x8 bv[4];
        const float* pw = W + (size_t)k0 * DIM + d_b0;
        #pragma unroll
        for (int nf = 0; nf < 4; ++nf) {
            #pragma unroll
            for (int j = 0; j < 8; ++j)
                bv[nf][j] = (__bf16)pw[j * DIM + nf * 16];
        }
        #pragma unroll
        for (int mf = 0; mf < 2; ++mf)
            #pragma unroll
            for (int nf = 0; nf < 4; ++nf)
                acc2[mf][nf] = __builtin_amdgcn_mfma_f32_16x16x32_bf16(av[mf], bv[nf], acc2[mf][nf], 0, 0, 0);
    }
    // nodes @ B  (K=128)
    #pragma unroll
    for (int ks = 0; ks < 4; ++ks) {
        const int k0 = ks * 32 + quad * 8;
        bf16x8 av[2];
        #pragma unroll
        for (int mf = 0; mf < 2; ++mf) {
            const float* p = nodes_b + (size_t)(i0 + wm * 32 + mf * 16 + lrow) * DIM + k0;
            const float4 f1 = *(const float4*)p;
            const float4 f2 = *(const float4*)(p + 4);
            av[mf][0] = (__bf16)f1.x; av[mf][1] = (__bf16)f1.y;
            av[mf][2] = (__bf16)f1.z; av[mf][3] = (__bf16)f1.w;
            av[mf][4] = (__bf16)f2.x; av[mf][5] = (__bf16)f2.y;
            av[mf][6] = (__bf16)f2.z; av[mf][7] = (__bf16)f2.w;
        }
        bf16x8 bv[4];
        const float* pB = Bm + (size_t)k0 * DIM + d_b0;
        #pragma unroll
        for (int nf = 0; nf < 4; ++nf) {
            #pragma unroll
            for (int j = 0; j < 8; ++j)
                bv[nf][j] = (__bf16)pB[j * DIM + nf * 16];
        }
        #pragma unroll
        for (int mf = 0; mf < 2; ++mf)
            #pragma unroll
            for (int nf = 0; nf < 4; ++nf)
                acc2[mf][nf] = __builtin_amdgcn_mfma_f32_16x16x32_bf16(av[mf], bv[nf], acc2[mf][nf], 0, 0, 0);
    }

    // leaky-relu + store
    float* out_b = out + (size_t)batch * SEQ * DIM;
    #pragma unroll
    for (int mf = 0; mf < 2; ++mf) {
        #pragma unroll
        for (int nf = 0; nf < 4; ++nf) {
            const int col = wn * 64 + nf * 16 + lrow;
            #pragma unroll
            for (int r = 0; r < 4; ++r) {
                const int row = i0 + wm * 32 + mf * 16 + quad * 4 + r;
                const float x = acc2[mf][nf][r];
                out_b[(size_t)row * DIM + col] = (x > 0.0f) ? x : NEG_SLOPE * x;
            }
        }
    }
}

extern "C" void kernel_launch(void* const* d_in, const int* in_sizes, int n_in,
                              void* d_out, int out_size, void* d_ws, size_t ws_size,
                              hipStream_t stream) {
    const float* nodes = (const float*)d_in[0];
    const int*   adj   = (const int*)d_in[1];
    const float* W     = (const float*)d_in[2];
    const float* Bm    = (const float*)d_in[3];
    float*       out   = (float*)d_out;
    gcn_fused<<<dim3(256), dim3(512), 0, stream>>>(nodes, adj, W, Bm, out);
}

// Round 9
// 218.680 us; speedup vs baseline: 2.3948x; 1.0039x over previous
//
#include <hip/hip_runtime.h>
#include <hip/hip_bf16.h>

#define SEQ 1024
#define DIM 128
#define NEG_SLOPE 0.1f

typedef __bf16 bf16x8 __attribute__((ext_vector_type(8)));
typedef float f32x4v __attribute__((ext_vector_type(4)));

// Main-loop LDS: double-buffered {mask_t 128i x 64o bf16 (16KB) + nodes_t 128d x 64o (16KB)}
// Row stride 128 B = 8 x 16B units, XOR-swizzled (verified r2/r8 scheme).
#define BUF_STRIDE 32768
#define NODES_OFF  16384

__device__ __forceinline__ int fxv(int x) {
    return ((x & 3) | ((x & 1) << 2)) ^ ((x >> 2) & 7);
}
__device__ __forceinline__ int swz(int row, int unit) {        // 128B-stride rows
    return row * 128 + ((unit ^ fxv(row >> 2)) << 4);
}
__device__ __forceinline__ int swz256(int row, int unit) {     // 256B-stride rows
    return row * 256 + ((unit ^ fxv(row >> 2)) << 4);
}
// Raw barrier: LDS-drain only — no vmcnt(0), register prefetch stays in flight
__device__ __forceinline__ void bar() {
    asm volatile("s_waitcnt lgkmcnt(0)" ::: "memory");
    __builtin_amdgcn_s_barrier();
    __builtin_amdgcn_sched_barrier(0);
}
__device__ __forceinline__ unsigned short bfb(float f) {
    __bf16 h = (__bf16)f;
    return __builtin_bit_cast(unsigned short, h);
}
__device__ __forceinline__ unsigned bpack(float a, float b) {
    return (unsigned)bfb(a) | ((unsigned)bfb(b) << 16);
}
__device__ __forceinline__ unsigned mpack(int x0, int x1) {
    unsigned m0 = (x0 != 0) ? 0x3F80u : 0u;   // bf16 1.0
    unsigned m1 = (x1 != 0) ? 0x3F80u : 0u;
    return m0 | (m1 << 16);
}

// 128-i tile, 512 threads (8 waves: wm 0..3 x wn 0..1), grid 256 = 1 block/CU.
// __launch_bounds__(512,1): grid is 1 block/CU anyway; min-waves=1 gives the
// 256-VGPR budget so the staging registers (A0/A1/N0/N1 + acc ~= 140 live) do
// NOT spill to scratch. (512,2) capped at 128 and spilled -> hidden scratch
// round-trips in the chunk loop (VGPR_Count 52-64 in all prior rocprof rows).
__global__ __launch_bounds__(512, 1)
void gcn_fused(const float* __restrict__ nodes,
               const int* __restrict__ adj,
               const float* __restrict__ W,
               const float* __restrict__ Bm,
               float* __restrict__ out)
{
    __shared__ alignas(16) unsigned char lds[2 * BUF_STRIDE];

    // XCD swizzle: all 8 i-tiles of a batch on one XCD (adj/nodes L2 locality)
    const int bid   = blockIdx.x;          // 256 = 32 batches x 8 itiles
    const int xcd   = bid & 7;
    const int slot  = bid >> 3;            // 0..31
    const int batch = ((slot >> 3) << 3) | xcd;   // [0,32)
    const int itile = slot & 7;            // [0,8)
    const int i0    = itile << 7;

    const int tid  = threadIdx.x;
    const int wave = tid >> 6;             // 0..7
    const int lane = tid & 63;
    const int wm   = wave >> 1;            // 0..3  (i 32-row slice)
    const int wn   = wave & 1;             // 0..1  (d 64-col slice)
    const int lrow = lane & 15;
    const int quad = lane >> 4;

    const int*   __restrict__ adj_b   = adj   + (size_t)batch * SEQ * SEQ;
    const float* __restrict__ nodes_b = nodes + (size_t)batch * SEQ * DIM;

    // staging thread mapping: 512 threads cover 64o x 128(i or d) per chunk
    const int a_row = (tid >> 5) * 4;      // o row group
    const int a_col = (tid & 31) * 4;      // i group (int4)
    const int n_col = (tid & 31) * 4;      // d group (float4)
    const int unit_s = (tid >> 5) >> 1;    // 16B unit of o-col in LDS row
    const int sub_s  = ((tid >> 5) & 1) * 8;

    f32x4v acc[2][4] = {};
    f32x4v acc_cnt[2] = {};
    bf16x8 ones;
    #pragma unroll
    for (int j = 0; j < 8; ++j) ones[j] = __builtin_bit_cast(__bf16, (unsigned short)0x3F80);

    // two named register staging sets (static indexing), 2-chunk prefetch
    int4   A0[4], A1[4];
    float4 N0[4], N1[4];

    auto load_chunk = [&](int o0, int4 (&A)[4], float4 (&N)[4]) {
        const int* pa = adj_b + (size_t)(o0 + a_row) * SEQ + (i0 + a_col);
        #pragma unroll
        for (int r = 0; r < 4; ++r) A[r] = *(const int4*)(pa + (size_t)r * SEQ);
        const float* pn = nodes_b + (size_t)(o0 + a_row) * DIM + n_col;
        #pragma unroll
        for (int r = 0; r < 4; ++r) N[r] = *(const float4*)(pn + (size_t)r * DIM);
    };

    auto write_lds = [&](int base, const int4 (&A)[4], const float4 (&N)[4]) {
        unsigned char* mb = lds + base;
        unsigned char* nb = lds + base + NODES_OFF;
        #pragma unroll
        for (int j = 0; j < 4; ++j) {
            uint2 w;
            w.x = mpack(((const int*)&A[0])[j], ((const int*)&A[1])[j]);
            w.y = mpack(((const int*)&A[2])[j], ((const int*)&A[3])[j]);
            *(uint2*)(mb + swz(a_col + j, unit_s) + sub_s) = w;
        }
        #pragma unroll
        for (int j = 0; j < 4; ++j) {
            uint2 w;
            w.x = bpack(((const float*)&N[0])[j], ((const float*)&N[1])[j]);
            w.y = bpack(((const float*)&N[2])[j], ((const float*)&N[3])[j]);
            *(uint2*)(nb + swz(n_col + j, unit_s) + sub_s) = w;
        }
    };

    auto compute = [&](int base) {
        const unsigned char* mb = lds + base;
        const unsigned char* nb = lds + base + NODES_OFF;
        #pragma unroll
        for (int kk = 0; kk < 2; ++kk) {
            bf16x8 av[2], bv[4];
            #pragma unroll
            for (int mf = 0; mf < 2; ++mf)
                av[mf] = *(const bf16x8*)(mb + swz(wm * 32 + mf * 16 + lrow, 4 * kk + quad));
            #pragma unroll
            for (int nf = 0; nf < 4; ++nf)
                bv[nf] = *(const bf16x8*)(nb + swz(wn * 64 + nf * 16 + lrow, 4 * kk + quad));
            #pragma unroll
            for (int mf = 0; mf < 2; ++mf) {
                #pragma unroll
                for (int nf = 0; nf < 4; ++nf)
                    acc[mf][nf] = __builtin_amdgcn_mfma_f32_16x16x32_bf16(av[mf], bv[nf], acc[mf][nf], 0, 0, 0);
                acc_cnt[mf] = __builtin_amdgcn_mfma_f32_16x16x32_bf16(av[mf], ones, acc_cnt[mf], 0, 0, 0);
            }
        }
    };

    // prologue: R0<-c0, R1<-c1; stage c0; R0<-c2  (2-deep in flight)
    load_chunk(0,   A0, N0);
    load_chunk(64,  A1, N1);
    write_lds(0, A0, N0);
    load_chunk(128, A0, N0);
    bar();

    for (int cc = 0; cc < 8; ++cc) {
        const int c0 = cc * 2;
        compute(0);
        write_lds(BUF_STRIDE, A1, N1);
        if (c0 + 3 < 16) load_chunk((c0 + 3) * 64, A1, N1);
        bar();
        compute(BUF_STRIDE);
        if (c0 + 2 < 16) write_lds(0, A0, N0);
        if (c0 + 4 < 16) load_chunk((c0 + 4) * 64, A0, N0);
        bar();
    }

    // ---- epilogue: pooled (32KB swizzled @0) + WT (32KB @32K), then W-matmul;
    //      then BT (32KB @0, pooled dead) and B-matmul. ----

    // pooled[128][128] bf16, 256B swizzled rows
    #pragma unroll
    for (int mf = 0; mf < 2; ++mf) {
        #pragma unroll
        for (int r = 0; r < 4; ++r) {
            const int row = wm * 32 + mf * 16 + quad * 4 + r;
            const float cnt = acc_cnt[mf][r];
            const float inv = (cnt > 0.5f) ? 1.0f / cnt : 0.0f;
            #pragma unroll
            for (int nf = 0; nf < 4; ++nf) {
                const int col = wn * 64 + nf * 16 + lrow;
                *(unsigned short*)(lds + row * 256 + ((((col >> 3) ^ fxv(row >> 2)) << 4))
                                   + (col & 7) * 2) = bfb(acc[mf][nf][r] * inv);
            }
        }
    }

    // stage WT[n][k] bf16 (transposed) into lds+32K: thread reads 8 W-rows x 16B
    const int n4 = (tid & 31) * 4;
    const int kg = tid >> 5;              // 0..15, covers k = kg*8..kg*8+7
    {
        float4 v[8];
        const float* pw = W + (size_t)(kg * 8) * DIM + n4;
        #pragma unroll
        for (int r = 0; r < 8; ++r) v[r] = *(const float4*)(pw + (size_t)r * DIM);
        #pragma unroll
        for (int j = 0; j < 4; ++j) {
            uint4 u;
            u.x = bpack(((const float*)&v[0])[j], ((const float*)&v[1])[j]);
            u.y = bpack(((const float*)&v[2])[j], ((const float*)&v[3])[j]);
            u.z = bpack(((const float*)&v[4])[j], ((const float*)&v[5])[j]);
            u.w = bpack(((const float*)&v[6])[j], ((const float*)&v[7])[j]);
            *(uint4*)(lds + BUF_STRIDE + swz256(n4 + j, kg)) = u;
        }
    }
    bar();

    f32x4v acc2[2][4] = {};

    // pooled @ W  (K=128): all operands from LDS b128 reads
    #pragma unroll
    for (int ks = 0; ks < 4; ++ks) {
        const int un = ks * 4 + quad;     // 16B unit for k0 = ks*32 + quad*8
        bf16x8 av[2], bv[4];
        #pragma unroll
        for (int mf = 0; mf < 2; ++mf)
            av[mf] = *(const bf16x8*)(lds + swz256(wm * 32 + mf * 16 + lrow, un));
        #pragma unroll
        for (int nf = 0; nf < 4; ++nf)
            bv[nf] = *(const bf16x8*)(lds + BUF_STRIDE + swz256(wn * 64 + nf * 16 + lrow, un));
        #pragma unroll
        for (int mf = 0; mf < 2; ++mf)
            #pragma unroll
            for (int nf = 0; nf < 4; ++nf)
                acc2[mf][nf] = __builtin_amdgcn_mfma_f32_16x16x32_bf16(av[mf], bv[nf], acc2[mf][nf], 0, 0, 0);
    }
    bar();   // all waves done reading pooled before BT overwrites it

    // stage BT[n][k] bf16 into lds+0 (pooled region, now dead)
    {
        float4 v[8];
        const float* pb = Bm + (size_t)(kg * 8) * DIM + n4;
        #pragma unroll
        for (int r = 0; r < 8; ++r) v[r] = *(const float4*)(pb + (size_t)r * DIM);
        #pragma unroll
        for (int j = 0; j < 4; ++j) {
            uint4 u;
            u.x = bpack(((const float*)&v[0])[j], ((const float*)&v[1])[j]);
            u.y = bpack(((const float*)&v[2])[j], ((const float*)&v[3])[j]);
            u.z = bpack(((const float*)&v[4])[j], ((const float*)&v[5])[j]);
            u.w = bpack(((const float*)&v[6])[j], ((const float*)&v[7])[j]);
            *(uint4*)(lds + swz256(n4 + j, kg)) = u;
        }
    }
    bar();

    // nodes @ B  (K=128): av from global f32 (L2-hot), bv from LDS
    #pragma unroll
    for (int ks = 0; ks < 4; ++ks) {
        const int k0 = ks * 32 + quad * 8;
        const int un = ks * 4 + quad;
        bf16x8 av[2], bv[4];
        #pragma unroll
        for (int mf = 0; mf < 2; ++mf) {
            const float* p = nodes_b + (size_t)(i0 + wm * 32 + mf * 16 + lrow) * DIM + k0;
            const float4 f1 = *(const float4*)p;
            const float4 f2 = *(const float4*)(p + 4);
            av[mf][0] = (__bf16)f1.x; av[mf][1] = (__bf16)f1.y;
            av[mf][2] = (__bf16)f1.z; av[mf][3] = (__bf16)f1.w;
            av[mf][4] = (__bf16)f2.x; av[mf][5] = (__bf16)f2.y;
            av[mf][6] = (__bf16)f2.z; av[mf][7] = (__bf16)f2.w;
        }
        #pragma unroll
        for (int nf = 0; nf < 4; ++nf)
            bv[nf] = *(const bf16x8*)(lds + swz256(wn * 64 + nf * 16 + lrow, un));
        #pragma unroll
        for (int mf = 0; mf < 2; ++mf)
            #pragma unroll
            for (int nf = 0; nf < 4; ++nf)
                acc2[mf][nf] = __builtin_amdgcn_mfma_f32_16x16x32_bf16(av[mf], bv[nf], acc2[mf][nf], 0, 0, 0);
    }

    // leaky-relu + store
    float* out_b = out + (size_t)batch * SEQ * DIM;
    #pragma unroll
    for (int mf = 0; mf < 2; ++mf) {
        #pragma unroll
        for (int nf = 0; nf < 4; ++nf) {
            const int col = wn * 64 + nf * 16 + lrow;
            #pragma unroll
            for (int r = 0; r < 4; ++r) {
                const int row = i0 + wm * 32 + mf * 16 + quad * 4 + r;
                const float x = acc2[mf][nf][r];
                out_b[(size_t)row * DIM + col] = (x > 0.0f) ? x : NEG_SLOPE * x;
            }
        }
    }
}

extern "C" void kernel_launch(void* const* d_in, const int* in_sizes, int n_in,
                              void* d_out, int out_size, void* d_ws, size_t ws_size,
                              hipStream_t stream) {
    const float* nodes = (const float*)d_in[0];
    const int*   adj   = (const int*)d_in[1];
    const float* W     = (const float*)d_in[2];
    const float* Bm    = (const float*)d_in[3];
    float*       out   = (float*)d_out;
    gcn_fused<<<dim3(256), dim3(512), 0, stream>>>(nodes, adj, W, Bm, out);
}

// Round 10
// 215.160 us; speedup vs baseline: 2.4340x; 1.0164x over previous
//
#include <hip/hip_runtime.h>
#include <hip/hip_bf16.h>

#define SEQ 1024
#define DIM 128
#define NEG_SLOPE 0.1f

typedef __bf16 bf16x8 __attribute__((ext_vector_type(8)));
typedef float f32x4v __attribute__((ext_vector_type(4)));
typedef int   i32x4  __attribute__((ext_vector_type(4)));

// Main-loop LDS: double-buffered {mask_t 128i x 64o bf16 (16KB) + nodes_t 128d x 64o (16KB)}
// Row stride 128 B = 8 x 16B units, XOR-swizzled (verified r2/r8/r9 scheme).
#define BUF_STRIDE 32768
#define NODES_OFF  16384

__device__ __forceinline__ int fxv(int x) {
    return ((x & 3) | ((x & 1) << 2)) ^ ((x >> 2) & 7);
}
__device__ __forceinline__ int swz(int row, int unit) {        // 128B-stride rows
    return row * 128 + ((unit ^ fxv(row >> 2)) << 4);
}
__device__ __forceinline__ int swz256(int row, int unit) {     // 256B-stride rows
    return row * 256 + ((unit ^ fxv(row >> 2)) << 4);
}
// Raw barrier: LDS-drain only — no vmcnt(0), register prefetch stays in flight
__device__ __forceinline__ void bar() {
    asm volatile("s_waitcnt lgkmcnt(0)" ::: "memory");
    __builtin_amdgcn_s_barrier();
    __builtin_amdgcn_sched_barrier(0);
}
__device__ __forceinline__ unsigned short bfb(float f) {
    __bf16 h = (__bf16)f;
    return __builtin_bit_cast(unsigned short, h);
}
__device__ __forceinline__ unsigned bpack(float a, float b) {
    return (unsigned)bfb(a) | ((unsigned)bfb(b) << 16);
}
__device__ __forceinline__ unsigned mpack(int x0, int x1) {
    unsigned m0 = (x0 != 0) ? 0x3F80u : 0u;   // bf16 1.0
    unsigned m1 = (x1 != 0) ? 0x3F80u : 0u;
    return m0 | (m1 << 16);
}

// 128-i tile, 512 threads (8 waves: wm 0..3 x wn 0..1), grid 256 = 1 block/CU.
// adj (134 MB, zero reuse) is loaded NON-TEMPORAL so its stream stops evicting
// the batch's 512 KB nodes slice from the XCD L2 — the 8 co-XCD i-tile blocks
// re-stage that slice 8x, and those re-reads are the 134 MB of avoidable
// fabric traffic that kept every structural variant pinned at ~62-80 us.
// out (write-once) is non-temporal too.
__global__ __launch_bounds__(512, 1)
void gcn_fused(const float* __restrict__ nodes,
               const int* __restrict__ adj,
               const float* __restrict__ W,
               const float* __restrict__ Bm,
               float* __restrict__ out)
{
    __shared__ alignas(16) unsigned char lds[2 * BUF_STRIDE];

    // XCD swizzle: all 8 i-tiles of a batch on one XCD (nodes L2 locality)
    const int bid   = blockIdx.x;          // 256 = 32 batches x 8 itiles
    const int xcd   = bid & 7;
    const int slot  = bid >> 3;            // 0..31
    const int batch = ((slot >> 3) << 3) | xcd;   // [0,32)
    const int itile = slot & 7;            // [0,8)
    const int i0    = itile << 7;

    const int tid  = threadIdx.x;
    const int wave = tid >> 6;             // 0..7
    const int lane = tid & 63;
    const int wm   = wave >> 1;            // 0..3  (i 32-row slice)
    const int wn   = wave & 1;             // 0..1  (d 64-col slice)
    const int lrow = lane & 15;
    const int quad = lane >> 4;

    const int*   __restrict__ adj_b   = adj   + (size_t)batch * SEQ * SEQ;
    const float* __restrict__ nodes_b = nodes + (size_t)batch * SEQ * DIM;

    // staging thread mapping: 512 threads cover 64o x 128(i or d) per chunk
    const int a_row = (tid >> 5) * 4;      // o row group
    const int a_col = (tid & 31) * 4;      // i group (int4)
    const int n_col = (tid & 31) * 4;      // d group (float4)
    const int unit_s = (tid >> 5) >> 1;    // 16B unit of o-col in LDS row
    const int sub_s  = ((tid >> 5) & 1) * 8;

    f32x4v acc[2][4] = {};
    f32x4v acc_cnt[2] = {};
    bf16x8 ones;
    #pragma unroll
    for (int j = 0; j < 8; ++j) ones[j] = __builtin_bit_cast(__bf16, (unsigned short)0x3F80);

    // two named register staging sets (static indexing), 2-chunk prefetch
    i32x4  A0[4], A1[4];
    float4 N0[4], N1[4];

    auto load_chunk = [&](int o0, i32x4 (&A)[4], float4 (&N)[4]) {
        const int* pa = adj_b + (size_t)(o0 + a_row) * SEQ + (i0 + a_col);
        #pragma unroll
        for (int r = 0; r < 4; ++r)
            A[r] = __builtin_nontemporal_load((const i32x4*)(pa + (size_t)r * SEQ));
        const float* pn = nodes_b + (size_t)(o0 + a_row) * DIM + n_col;
        #pragma unroll
        for (int r = 0; r < 4; ++r) N[r] = *(const float4*)(pn + (size_t)r * DIM);
    };

    auto write_lds = [&](int base, const i32x4 (&A)[4], const float4 (&N)[4]) {
        unsigned char* mb = lds + base;
        unsigned char* nb = lds + base + NODES_OFF;
        #pragma unroll
        for (int j = 0; j < 4; ++j) {
            uint2 w;
            w.x = mpack(A[0][j], A[1][j]);
            w.y = mpack(A[2][j], A[3][j]);
            *(uint2*)(mb + swz(a_col + j, unit_s) + sub_s) = w;
        }
        #pragma unroll
        for (int j = 0; j < 4; ++j) {
            uint2 w;
            w.x = bpack(((const float*)&N[0])[j], ((const float*)&N[1])[j]);
            w.y = bpack(((const float*)&N[2])[j], ((const float*)&N[3])[j]);
            *(uint2*)(nb + swz(n_col + j, unit_s) + sub_s) = w;
        }
    };

    auto compute = [&](int base) {
        const unsigned char* mb = lds + base;
        const unsigned char* nb = lds + base + NODES_OFF;
        #pragma unroll
        for (int kk = 0; kk < 2; ++kk) {
            bf16x8 av[2], bv[4];
            #pragma unroll
            for (int mf = 0; mf < 2; ++mf)
                av[mf] = *(const bf16x8*)(mb + swz(wm * 32 + mf * 16 + lrow, 4 * kk + quad));
            #pragma unroll
            for (int nf = 0; nf < 4; ++nf)
                bv[nf] = *(const bf16x8*)(nb + swz(wn * 64 + nf * 16 + lrow, 4 * kk + quad));
            #pragma unroll
            for (int mf = 0; mf < 2; ++mf) {
                #pragma unroll
                for (int nf = 0; nf < 4; ++nf)
                    acc[mf][nf] = __builtin_amdgcn_mfma_f32_16x16x32_bf16(av[mf], bv[nf], acc[mf][nf], 0, 0, 0);
                acc_cnt[mf] = __builtin_amdgcn_mfma_f32_16x16x32_bf16(av[mf], ones, acc_cnt[mf], 0, 0, 0);
            }
        }
    };

    // prologue: R0<-c0, R1<-c1; stage c0; R0<-c2  (2-deep in flight)
    load_chunk(0,   A0, N0);
    load_chunk(64,  A1, N1);
    write_lds(0, A0, N0);
    load_chunk(128, A0, N0);
    bar();

    for (int cc = 0; cc < 8; ++cc) {
        const int c0 = cc * 2;
        compute(0);
        write_lds(BUF_STRIDE, A1, N1);
        if (c0 + 3 < 16) load_chunk((c0 + 3) * 64, A1, N1);
        bar();
        compute(BUF_STRIDE);
        if (c0 + 2 < 16) write_lds(0, A0, N0);
        if (c0 + 4 < 16) load_chunk((c0 + 4) * 64, A0, N0);
        bar();
    }

    // ---- epilogue: pooled (32KB swizzled @0) + WT (32KB @32K), then W-matmul;
    //      then BT (32KB @0, pooled dead) and B-matmul. ----

    // pooled[128][128] bf16, 256B swizzled rows
    #pragma unroll
    for (int mf = 0; mf < 2; ++mf) {
        #pragma unroll
        for (int r = 0; r < 4; ++r) {
            const int row = wm * 32 + mf * 16 + quad * 4 + r;
            const float cnt = acc_cnt[mf][r];
            const float inv = (cnt > 0.5f) ? 1.0f / cnt : 0.0f;
            #pragma unroll
            for (int nf = 0; nf < 4; ++nf) {
                const int col = wn * 64 + nf * 16 + lrow;
                *(unsigned short*)(lds + row * 256 + ((((col >> 3) ^ fxv(row >> 2)) << 4))
                                   + (col & 7) * 2) = bfb(acc[mf][nf][r] * inv);
            }
        }
    }

    // stage WT[n][k] bf16 (transposed) into lds+32K
    const int n4 = (tid & 31) * 4;
    const int kg = tid >> 5;              // 0..15, covers k = kg*8..kg*8+7
    {
        float4 v[8];
        const float* pw = W + (size_t)(kg * 8) * DIM + n4;
        #pragma unroll
        for (int r = 0; r < 8; ++r) v[r] = *(const float4*)(pw + (size_t)r * DIM);
        #pragma unroll
        for (int j = 0; j < 4; ++j) {
            uint4 u;
            u.x = bpack(((const float*)&v[0])[j], ((const float*)&v[1])[j]);
            u.y = bpack(((const float*)&v[2])[j], ((const float*)&v[3])[j]);
            u.z = bpack(((const float*)&v[4])[j], ((const float*)&v[5])[j]);
            u.w = bpack(((const float*)&v[6])[j], ((const float*)&v[7])[j]);
            *(uint4*)(lds + BUF_STRIDE + swz256(n4 + j, kg)) = u;
        }
    }
    bar();

    f32x4v acc2[2][4] = {};

    // pooled @ W  (K=128): all operands from LDS b128 reads
    #pragma unroll
    for (int ks = 0; ks < 4; ++ks) {
        const int un = ks * 4 + quad;     // 16B unit for k0 = ks*32 + quad*8
        bf16x8 av[2], bv[4];
        #pragma unroll
        for (int mf = 0; mf < 2; ++mf)
            av[mf] = *(const bf16x8*)(lds + swz256(wm * 32 + mf * 16 + lrow, un));
        #pragma unroll
        for (int nf = 0; nf < 4; ++nf)
            bv[nf] = *(const bf16x8*)(lds + BUF_STRIDE + swz256(wn * 64 + nf * 16 + lrow, un));
        #pragma unroll
        for (int mf = 0; mf < 2; ++mf)
            #pragma unroll
            for (int nf = 0; nf < 4; ++nf)
                acc2[mf][nf] = __builtin_amdgcn_mfma_f32_16x16x32_bf16(av[mf], bv[nf], acc2[mf][nf], 0, 0, 0);
    }
    bar();   // all waves done reading pooled before BT overwrites it

    // stage BT[n][k] bf16 into lds+0 (pooled region, now dead)
    {
        float4 v[8];
        const float* pb = Bm + (size_t)(kg * 8) * DIM + n4;
        #pragma unroll
        for (int r = 0; r < 8; ++r) v[r] = *(const float4*)(pb + (size_t)r * DIM);
        #pragma unroll
        for (int j = 0; j < 4; ++j) {
            uint4 u;
            u.x = bpack(((const float*)&v[0])[j], ((const float*)&v[1])[j]);
            u.y = bpack(((const float*)&v[2])[j], ((const float*)&v[3])[j]);
            u.z = bpack(((const float*)&v[4])[j], ((const float*)&v[5])[j]);
            u.w = bpack(((const float*)&v[6])[j], ((const float*)&v[7])[j]);
            *(uint4*)(lds + swz256(n4 + j, kg)) = u;
        }
    }
    bar();

    // nodes @ B  (K=128): av from global f32 (L2-hot now that adj is nt), bv from LDS
    #pragma unroll
    for (int ks = 0; ks < 4; ++ks) {
        const int k0 = ks * 32 + quad * 8;
        const int un = ks * 4 + quad;
        bf16x8 av[2], bv[4];
        #pragma unroll
        for (int mf = 0; mf < 2; ++mf) {
            const float* p = nodes_b + (size_t)(i0 + wm * 32 + mf * 16 + lrow) * DIM + k0;
            const float4 f1 = *(const float4*)p;
            const float4 f2 = *(const float4*)(p + 4);
            av[mf][0] = (__bf16)f1.x; av[mf][1] = (__bf16)f1.y;
            av[mf][2] = (__bf16)f1.z; av[mf][3] = (__bf16)f1.w;
            av[mf][4] = (__bf16)f2.x; av[mf][5] = (__bf16)f2.y;
            av[mf][6] = (__bf16)f2.z; av[mf][7] = (__bf16)f2.w;
        }
        #pragma unroll
        for (int nf = 0; nf < 4; ++nf)
            bv[nf] = *(const bf16x8*)(lds + swz256(wn * 64 + nf * 16 + lrow, un));
        #pragma unroll
        for (int mf = 0; mf < 2; ++mf)
            #pragma unroll
            for (int nf = 0; nf < 4; ++nf)
                acc2[mf][nf] = __builtin_amdgcn_mfma_f32_16x16x32_bf16(av[mf], bv[nf], acc2[mf][nf], 0, 0, 0);
    }

    // leaky-relu + non-temporal store (write-once, keep out of L2)
    float* out_b = out + (size_t)batch * SEQ * DIM;
    #pragma unroll
    for (int mf = 0; mf < 2; ++mf) {
        #pragma unroll
        for (int nf = 0; nf < 4; ++nf) {
            const int col = wn * 64 + nf * 16 + lrow;
            #pragma unroll
            for (int r = 0; r < 4; ++r) {
                const int row = i0 + wm * 32 + mf * 16 + quad * 4 + r;
                const float x = acc2[mf][nf][r];
                const float y = (x > 0.0f) ? x : NEG_SLOPE * x;
                __builtin_nontemporal_store(y, &out_b[(size_t)row * DIM + col]);
            }
        }
    }
}

extern "C" void kernel_launch(void* const* d_in, const int* in_sizes, int n_in,
                              void* d_out, int out_size, void* d_ws, size_t ws_size,
                              hipStream_t stream) {
    const float* nodes = (const float*)d_in[0];
    const int*   adj   = (const int*)d_in[1];
    const float* W     = (const float*)d_in[2];
    const float* Bm    = (const float*)d_in[3];
    float*       out   = (float*)d_out;
    gcn_fused<<<dim3(256), dim3(512), 0, stream>>>(nodes, adj, W, Bm, out);
}